// Round 1
// baseline (1428.836 us; speedup 1.0000x reference)
//
#include <hip/hip_runtime.h>
#include <math.h>

#define N_NODES 100000
#define N_EDGES 1600000
#define NEG_SLOPE 0.2f
#define EPS 1e-16f

__device__ __forceinline__ float lrelu(float v) { return v > 0.f ? v : NEG_SLOPE * v; }

// ---------------------------------------------------------------- zero init
__global__ void k_zero(float4* __restrict__ p, int n4) {
    int i = blockIdx.x * blockDim.x + threadIdx.x;
    if (i < n4) p[i] = make_float4(0.f, 0.f, 0.f, 0.f);
}

// ---------------------------------------------------------------- K1: per-node attention logits for layer 1
// wave per node: lane j handles h1 elements j and j+64 (recomputed from x, w1)
__global__ void k_node1(const float* __restrict__ x, const float* __restrict__ w1,
                        const float* __restrict__ as1, const float* __restrict__ ad1,
                        float* __restrict__ a1s, float* __restrict__ a1d) {
    __shared__ float w1s[384];
    int tid = threadIdx.x;
    for (int i = tid; i < 384; i += 256) w1s[i] = w1[i];
    __syncthreads();
    int wave = tid >> 6, lane = tid & 63;
    int n = blockIdx.x * 4 + wave;
    if (n >= N_NODES) return;
    float x0 = x[n * 3 + 0], x1 = x[n * 3 + 1], x2 = x[n * 3 + 2];
    int j = lane, j2 = lane + 64;
    float ha = x0 * w1s[j * 3] + x1 * w1s[j * 3 + 1] + x2 * w1s[j * 3 + 2];
    float hb = x0 * w1s[j2 * 3] + x1 * w1s[j2 * 3 + 1] + x2 * w1s[j2 * 3 + 2];
    // heads: element j -> head j>>5 (0/1); element j+64 -> head 2+(j>>5)
    float p0s = ha * as1[j], p1s = hb * as1[j2];
    float p0d = ha * ad1[j], p1d = hb * ad1[j2];
    #pragma unroll
    for (int off = 16; off; off >>= 1) {
        p0s += __shfl_xor(p0s, off);
        p1s += __shfl_xor(p1s, off);
        p0d += __shfl_xor(p0d, off);
        p1d += __shfl_xor(p1d, off);
    }
    if ((lane & 31) == 0) {
        int h = lane >> 5;  // 0 or 1
        a1s[n * 4 + h] = p0s; a1s[n * 4 + 2 + h] = p1s;
        a1d[n * 4 + h] = p0d; a1d[n * 4 + 2 + h] = p1d;
    }
}

// ---------------------------------------------------------------- K3: layer-1 edge scatter (wave per edge)
__global__ void k_edge1(const int* __restrict__ ei, const float* __restrict__ x,
                        const float* __restrict__ w1,
                        const float* __restrict__ a1s, const float* __restrict__ a1d,
                        float* __restrict__ agg1, float* __restrict__ den1) {
    __shared__ float w1s[384];
    int tid = threadIdx.x;
    for (int i = tid; i < 384; i += 256) w1s[i] = w1[i];
    __syncthreads();
    int wave = tid >> 6, lane = tid & 63;
    int e = blockIdx.x * 4 + wave;
    if (e >= N_EDGES) return;
    int src = ei[e], dst = ei[N_EDGES + e];
    float x0 = x[src * 3], x1 = x[src * 3 + 1], x2 = x[src * 3 + 2];
    float ex0 = __expf(lrelu(a1s[src * 4 + 0] + a1d[dst * 4 + 0]));
    float ex1 = __expf(lrelu(a1s[src * 4 + 1] + a1d[dst * 4 + 1]));
    float ex2 = __expf(lrelu(a1s[src * 4 + 2] + a1d[dst * 4 + 2]));
    float ex3 = __expf(lrelu(a1s[src * 4 + 3] + a1d[dst * 4 + 3]));
    int j = lane, j2 = lane + 64;
    float ha = x0 * w1s[j * 3] + x1 * w1s[j * 3 + 1] + x2 * w1s[j * 3 + 2];
    float hb = x0 * w1s[j2 * 3] + x1 * w1s[j2 * 3 + 1] + x2 * w1s[j2 * 3 + 2];
    float exA = (lane >> 5) ? ex1 : ex0;   // head of element j
    float exB = (lane >> 5) ? ex3 : ex2;   // head of element j+64
    atomicAdd(&agg1[dst * 128 + j], exA * ha);
    atomicAdd(&agg1[dst * 128 + j2], exB * hb);
    if (lane < 4) {
        float v = ex0;
        if (lane == 1) v = ex1;
        else if (lane == 2) v = ex2;
        else if (lane == 3) v = ex3;
        atomicAdd(&den1[dst * 4 + lane], v);
    }
}

// ---------------------------------------------------------------- K4: finalize L1 + ELU + h2 = f1 @ w2^T + L2 logits
__global__ void k_node2(const float* __restrict__ agg1, const float* __restrict__ den1,
                        const float* __restrict__ b1, const float* __restrict__ w2,
                        const float* __restrict__ as2, const float* __restrict__ ad2,
                        float* __restrict__ h2, float* __restrict__ a2s, float* __restrict__ a2d) {
    __shared__ float w2t[4096];     // transposed [k][o] -> conflict-free matvec reads
    __shared__ float f1s[4][128];
    int tid = threadIdx.x;
    for (int i = tid; i < 4096; i += 256) {
        int o = i >> 7, k = i & 127;
        w2t[k * 32 + o] = w2[i];
    }
    int wave = tid >> 6, lane = tid & 63;
    int n = blockIdx.x * 4 + wave;
    if (n < N_NODES) {
        int j = lane, j2 = lane + 64;
        float d0 = den1[n * 4 + (j >> 5)] + EPS;
        float d1 = den1[n * 4 + 2 + (j >> 5)] + EPS;
        float v0 = agg1[n * 128 + j] / d0 + b1[j];
        float v1 = agg1[n * 128 + j2] / d1 + b1[j2];
        f1s[wave][j]  = v0 > 0.f ? v0 : expm1f(v0);
        f1s[wave][j2] = v1 > 0.f ? v1 : expm1f(v1);
    }
    __syncthreads();
    if (n >= N_NODES) return;
    int o = lane & 31, half = lane >> 5;
    const float* f = f1s[wave];
    int k0 = half * 64;
    float acc = 0.f;
    #pragma unroll 8
    for (int t = 0; t < 64; t++)
        acc += f[k0 + t] * w2t[(k0 + t) * 32 + o];
    acc += __shfl_down(acc, 32);
    if (half == 0) {
        h2[n * 32 + o] = acc;
        float ps = acc * as2[o], pd = acc * ad2[o];
        #pragma unroll
        for (int off = 16; off; off >>= 1) {
            ps += __shfl_xor(ps, off);
            pd += __shfl_xor(pd, off);
        }
        if (o == 0) { a2s[n] = ps; a2d[n] = pd; }
    }
}

// ---------------------------------------------------------------- K5: layer-2 edge scatter (32 lanes per edge)
__global__ void k_edge2(const int* __restrict__ ei, const float* __restrict__ h2,
                        const float* __restrict__ a2s, const float* __restrict__ a2d,
                        float* __restrict__ agg2, float* __restrict__ den2) {
    int tid = threadIdx.x;
    int e = blockIdx.x * 8 + (tid >> 5);
    if (e >= N_EDGES) return;
    int c = tid & 31;
    int src = ei[e], dst = ei[N_EDGES + e];
    float ex = __expf(lrelu(a2s[src] + a2d[dst]));
    atomicAdd(&agg2[dst * 32 + c], ex * h2[src * 32 + c]);
    if (c == 0) atomicAdd(&den2[dst], ex);
}

// ---------------------------------------------------------------- K6: finalize layer 2 -> node features hf [N,32]
__global__ void k_fin2(const float* __restrict__ agg2, const float* __restrict__ den2,
                       const float* __restrict__ b2, float* __restrict__ hf) {
    int i = blockIdx.x * blockDim.x + threadIdx.x;
    if (i >= N_NODES * 32) return;
    int n = i >> 5, c = i & 31;
    hf[i] = agg2[i] / (den2[n] + EPS) + b2[c];
}

// ---------------------------------------------------------------- K7: edge MLP (lane per edge, uniform weight reads -> s_load)
__global__ void k_mlp(const int* __restrict__ ei, const float* __restrict__ hf,
                      const float* __restrict__ mw1, const float* __restrict__ mb1,
                      const float* __restrict__ mw2, const float* __restrict__ mb2,
                      float* __restrict__ out) {
    int e = blockIdx.x * blockDim.x + threadIdx.x;
    if (e >= N_EDGES) return;
    int src = ei[e], dst = ei[N_EDGES + e];
    float ef[64];
    const float4* ps = (const float4*)(hf + src * 32);
    const float4* pd = (const float4*)(hf + dst * 32);
    #pragma unroll
    for (int q = 0; q < 8; q++) {
        float4 v = ps[q];
        ef[q * 4 + 0] = v.x; ef[q * 4 + 1] = v.y; ef[q * 4 + 2] = v.z; ef[q * 4 + 3] = v.w;
    }
    #pragma unroll
    for (int q = 0; q < 8; q++) {
        float4 v = pd[q];
        ef[32 + q * 4 + 0] = v.x; ef[32 + q * 4 + 1] = v.y; ef[32 + q * 4 + 2] = v.z; ef[32 + q * 4 + 3] = v.w;
    }
    float s = 0.f;
    #pragma unroll 4
    for (int jj = 0; jj < 32; jj++) {
        float acc = mb1[jj];
        #pragma unroll
        for (int k = 0; k < 64; k++) acc += mw1[jj * 64 + k] * ef[k];
        s += fmaxf(acc, 0.f) * mw2[jj];
    }
    s += mb2[0];
    out[e] = fmaxf(s, 0.f);
}

// ---------------------------------------------------------------- launch
extern "C" void kernel_launch(void* const* d_in, const int* in_sizes, int n_in,
                              void* d_out, int out_size, void* d_ws, size_t ws_size,
                              hipStream_t stream) {
    const float* x    = (const float*)d_in[0];
    const int*   ei   = (const int*)d_in[1];
    const float* w1   = (const float*)d_in[2];
    const float* as1  = (const float*)d_in[3];
    const float* ad1  = (const float*)d_in[4];
    const float* b1   = (const float*)d_in[5];
    const float* w2   = (const float*)d_in[6];
    const float* as2  = (const float*)d_in[7];
    const float* ad2  = (const float*)d_in[8];
    const float* b2   = (const float*)d_in[9];
    const float* mw1  = (const float*)d_in[10];
    const float* mb1  = (const float*)d_in[11];
    const float* mw2  = (const float*)d_in[12];
    const float* mb2  = (const float*)d_in[13];
    float* out = (float*)d_out;

    const int N = N_NODES;
    float* ws   = (float*)d_ws;
    float* agg1 = ws;                  // N*128  (zeroed)
    float* den1 = agg1 + N * 128;      // N*4    (zeroed)
    float* agg2 = den1 + N * 4;        // N*32   (zeroed)
    float* den2 = agg2 + N * 32;       // N      (zeroed)
    float* a1s  = den2 + N;            // N*4
    float* a1d  = a1s + N * 4;         // N*4
    float* h2   = a1d + N * 4;         // N*32
    float* a2s  = h2 + N * 32;         // N
    float* a2d  = a2s + N;             // N
    float* hf   = a2d + N;             // N*32

    // zero the accumulator region (agg1|den1|agg2|den2 contiguous): N*165 floats
    int n4 = N * 165 / 4;
    k_zero<<<(n4 + 255) / 256, 256, 0, stream>>>((float4*)ws, n4);

    k_node1<<<(N + 3) / 4, 256, 0, stream>>>(x, w1, as1, ad1, a1s, a1d);

    k_edge1<<<(N_EDGES + 3) / 4, 256, 0, stream>>>(ei, x, w1, a1s, a1d, agg1, den1);

    k_node2<<<(N + 3) / 4, 256, 0, stream>>>(agg1, den1, b1, w2, as2, ad2, h2, a2s, a2d);

    k_edge2<<<(N_EDGES + 7) / 8, 256, 0, stream>>>(ei, h2, a2s, a2d, agg2, den2);

    k_fin2<<<(N * 32 + 255) / 256, 256, 0, stream>>>(agg2, den2, b2, hf);

    k_mlp<<<(N_EDGES + 255) / 256, 256, 0, stream>>>(ei, hf, mw1, mb1, mw2, mb2, out);
}

// Round 2
// 720.046 us; speedup vs baseline: 1.9844x; 1.9844x over previous
//
#include <hip/hip_runtime.h>
#include <math.h>

#define N_NODES 100000
#define N_EDGES 1600000
#define NEG_SLOPE 0.2f
#define EPS 1e-16f

__device__ __forceinline__ float lrelu(float v) { return v > 0.f ? v : NEG_SLOPE * v; }

// ---------------------------------------------------------------- zero deg
__global__ void k_zero_deg(int* __restrict__ deg) {
    int i = blockIdx.x * blockDim.x + threadIdx.x;
    if (i < N_NODES) deg[i] = 0;
}

// ---------------------------------------------------------------- histogram of dst
__global__ void k_hist(const int* __restrict__ ei, int* __restrict__ deg) {
    int e = blockIdx.x * blockDim.x + threadIdx.x;
    if (e < N_EDGES) atomicAdd(&deg[ei[N_EDGES + e]], 1);
}

// ---------------------------------------------------------------- scan level 1: per-256-chunk exclusive scan + chunk totals
__global__ void k_scan_part(const int* __restrict__ deg, int* __restrict__ loc,
                            int* __restrict__ partial) {
    __shared__ int tmp[256];
    int i = blockIdx.x * 256 + threadIdx.x;
    int v = (i < N_NODES) ? deg[i] : 0;
    tmp[threadIdx.x] = v;
    __syncthreads();
    for (int off = 1; off < 256; off <<= 1) {
        int t = (threadIdx.x >= off) ? tmp[threadIdx.x - off] : 0;
        __syncthreads();
        tmp[threadIdx.x] += t;
        __syncthreads();
    }
    if (i < N_NODES) loc[i] = tmp[threadIdx.x] - v;   // exclusive
    if (threadIdx.x == 255) partial[blockIdx.x] = tmp[255];
}

// ---------------------------------------------------------------- scan level 2: scan chunk totals (nb <= 512)
__global__ void k_scan_tot(int* __restrict__ partial, int nb) {
    __shared__ int tmp[512];
    int v = (threadIdx.x < nb) ? partial[threadIdx.x] : 0;
    tmp[threadIdx.x] = v;
    __syncthreads();
    for (int off = 1; off < 512; off <<= 1) {
        int t = (threadIdx.x >= off) ? tmp[threadIdx.x - off] : 0;
        __syncthreads();
        tmp[threadIdx.x] += t;
        __syncthreads();
    }
    if (threadIdx.x < nb) partial[threadIdx.x] = tmp[threadIdx.x] - v;  // exclusive
}

// ---------------------------------------------------------------- scan level 3: combine + init cursor
__global__ void k_scan_add(const int* __restrict__ loc, const int* __restrict__ partial,
                           int* __restrict__ rowptr, int* __restrict__ cursor) {
    int i = blockIdx.x * blockDim.x + threadIdx.x;
    if (i < N_NODES) {
        int r = loc[i] + partial[i >> 8];
        rowptr[i] = r;
        cursor[i] = r;
    }
}

// ---------------------------------------------------------------- scatter edges into CSR slots (by dst)
__global__ void k_scatter(const int* __restrict__ ei, int* __restrict__ cursor,
                          int* __restrict__ csr_src) {
    int e = blockIdx.x * blockDim.x + threadIdx.x;
    if (e < N_EDGES) {
        int dst = ei[N_EDGES + e];
        int pos = atomicAdd(&cursor[dst], 1);
        csr_src[pos] = ei[e];
    }
}

// ---------------------------------------------------------------- K1: per-node attention logits for layer 1
__global__ void k_node1(const float* __restrict__ x, const float* __restrict__ w1,
                        const float* __restrict__ as1, const float* __restrict__ ad1,
                        float* __restrict__ a1s, float* __restrict__ a1d) {
    __shared__ float w1s[384];
    int tid = threadIdx.x;
    for (int i = tid; i < 384; i += 256) w1s[i] = w1[i];
    __syncthreads();
    int wave = tid >> 6, lane = tid & 63;
    int n = blockIdx.x * 4 + wave;
    if (n >= N_NODES) return;
    float x0 = x[n * 3 + 0], x1 = x[n * 3 + 1], x2 = x[n * 3 + 2];
    int j = lane, j2 = lane + 64;
    float ha = x0 * w1s[j * 3] + x1 * w1s[j * 3 + 1] + x2 * w1s[j * 3 + 2];
    float hb = x0 * w1s[j2 * 3] + x1 * w1s[j2 * 3 + 1] + x2 * w1s[j2 * 3 + 2];
    float p0s = ha * as1[j], p1s = hb * as1[j2];
    float p0d = ha * ad1[j], p1d = hb * ad1[j2];
    #pragma unroll
    for (int off = 16; off; off >>= 1) {
        p0s += __shfl_xor(p0s, off);
        p1s += __shfl_xor(p1s, off);
        p0d += __shfl_xor(p0d, off);
        p1d += __shfl_xor(p1d, off);
    }
    if ((lane & 31) == 0) {
        int h = lane >> 5;
        a1s[n * 4 + h] = p0s; a1s[n * 4 + 2 + h] = p1s;
        a1d[n * 4 + h] = p0d; a1d[n * 4 + 2 + h] = p1d;
    }
}

// ---------------------------------------------------------------- K-GAT1: layer-1 gather + finalize + ELU + w2 matvec + L2 logits
// wave per dst node; lane j handles h1 elements j, j+64
__global__ void k_gat1(const int* __restrict__ rowptr, const int* __restrict__ deg,
                       const int* __restrict__ csr_src,
                       const float* __restrict__ x, const float* __restrict__ w1,
                       const float* __restrict__ a1s, const float* __restrict__ a1d,
                       const float* __restrict__ b1, const float* __restrict__ w2,
                       const float* __restrict__ as2, const float* __restrict__ ad2,
                       float* __restrict__ h2, float* __restrict__ a2s, float* __restrict__ a2d) {
    __shared__ float w1s[384];
    __shared__ float w2t[4096];   // transposed [k][o]
    __shared__ float f1s[4][128];
    int tid = threadIdx.x;
    for (int i = tid; i < 384; i += 256) w1s[i] = w1[i];
    for (int i = tid; i < 4096; i += 256) {
        int o = i >> 7, k = i & 127;
        w2t[k * 32 + o] = w2[i];
    }
    __syncthreads();
    int wave = tid >> 6, lane = tid & 63;
    int n = blockIdx.x * 4 + wave;
    if (n < N_NODES) {
        int j = lane, j2 = lane + 64;
        int h0 = j >> 5;                           // head of elem j; elem j2 head = 2+h0
        float wa0 = w1s[j * 3], wa1 = w1s[j * 3 + 1], wa2 = w1s[j * 3 + 2];
        float wb0 = w1s[j2 * 3], wb1 = w1s[j2 * 3 + 1], wb2 = w1s[j2 * 3 + 2];
        float adA = a1d[n * 4 + h0], adB = a1d[n * 4 + 2 + h0];
        int beg = rowptr[n], cnt = deg[n];
        float acc0 = 0.f, acc1 = 0.f, dA = 0.f, dB = 0.f;
        for (int t = 0; t < cnt; t++) {
            int s = csr_src[beg + t];
            float exA = __expf(lrelu(a1s[s * 4 + h0] + adA));
            float exB = __expf(lrelu(a1s[s * 4 + 2 + h0] + adB));
            float x0 = x[s * 3], x1 = x[s * 3 + 1], x2 = x[s * 3 + 2];
            float ha = x0 * wa0 + x1 * wa1 + x2 * wa2;
            float hb = x0 * wb0 + x1 * wb1 + x2 * wb2;
            acc0 += exA * ha; acc1 += exB * hb;
            dA += exA; dB += exB;
        }
        float v0 = acc0 / (dA + EPS) + b1[j];
        float v1 = acc1 / (dB + EPS) + b1[j2];
        f1s[wave][j]  = v0 > 0.f ? v0 : expm1f(v0);
        f1s[wave][j2] = v1 > 0.f ? v1 : expm1f(v1);
    }
    __syncthreads();
    if (n >= N_NODES) return;
    int o = lane & 31, half = lane >> 5;
    const float* f = f1s[wave];
    int k0 = half * 64;
    float acc = 0.f;
    #pragma unroll 8
    for (int t = 0; t < 64; t++)
        acc += f[k0 + t] * w2t[(k0 + t) * 32 + o];
    acc += __shfl_down(acc, 32);
    if (half == 0) {
        h2[n * 32 + o] = acc;
        float ps = acc * as2[o], pd = acc * ad2[o];
        #pragma unroll
        for (int off = 16; off; off >>= 1) {
            ps += __shfl_xor(ps, off);
            pd += __shfl_xor(pd, off);
        }
        if (o == 0) { a2s[n] = ps; a2d[n] = pd; }
    }
}

// ---------------------------------------------------------------- K-GAT2: layer-2 gather + finalize (half-wave per node)
__global__ void k_gat2(const int* __restrict__ rowptr, const int* __restrict__ deg,
                       const int* __restrict__ csr_src,
                       const float* __restrict__ h2, const float* __restrict__ a2s,
                       const float* __restrict__ a2d, const float* __restrict__ b2,
                       float* __restrict__ hf) {
    int tid = threadIdx.x;
    int n = blockIdx.x * 8 + (tid >> 5);
    if (n >= N_NODES) return;
    int c = tid & 31;
    float ad = a2d[n];
    int beg = rowptr[n], cnt = deg[n];
    float acc = 0.f, den = 0.f;
    for (int t = 0; t < cnt; t++) {
        int s = csr_src[beg + t];
        float ex = __expf(lrelu(a2s[s] + ad));
        acc += ex * h2[s * 32 + c];
        den += ex;
    }
    hf[n * 32 + c] = acc / (den + EPS) + b2[c];
}

// ---------------------------------------------------------------- K7: edge MLP (lane per edge)
__global__ void k_mlp(const int* __restrict__ ei, const float* __restrict__ hf,
                      const float* __restrict__ mw1, const float* __restrict__ mb1,
                      const float* __restrict__ mw2, const float* __restrict__ mb2,
                      float* __restrict__ out) {
    int e = blockIdx.x * blockDim.x + threadIdx.x;
    if (e >= N_EDGES) return;
    int src = ei[e], dst = ei[N_EDGES + e];
    float ef[64];
    const float4* ps = (const float4*)(hf + src * 32);
    const float4* pd = (const float4*)(hf + dst * 32);
    #pragma unroll
    for (int q = 0; q < 8; q++) {
        float4 v = ps[q];
        ef[q * 4 + 0] = v.x; ef[q * 4 + 1] = v.y; ef[q * 4 + 2] = v.z; ef[q * 4 + 3] = v.w;
    }
    #pragma unroll
    for (int q = 0; q < 8; q++) {
        float4 v = pd[q];
        ef[32 + q * 4 + 0] = v.x; ef[32 + q * 4 + 1] = v.y; ef[32 + q * 4 + 2] = v.z; ef[32 + q * 4 + 3] = v.w;
    }
    float s = 0.f;
    #pragma unroll 4
    for (int jj = 0; jj < 32; jj++) {
        float acc = mb1[jj];
        #pragma unroll
        for (int k = 0; k < 64; k++) acc += mw1[jj * 64 + k] * ef[k];
        s += fmaxf(acc, 0.f) * mw2[jj];
    }
    s += mb2[0];
    out[e] = fmaxf(s, 0.f);
}

// ---------------------------------------------------------------- launch
extern "C" void kernel_launch(void* const* d_in, const int* in_sizes, int n_in,
                              void* d_out, int out_size, void* d_ws, size_t ws_size,
                              hipStream_t stream) {
    const float* x    = (const float*)d_in[0];
    const int*   ei   = (const int*)d_in[1];
    const float* w1   = (const float*)d_in[2];
    const float* as1  = (const float*)d_in[3];
    const float* ad1  = (const float*)d_in[4];
    const float* b1   = (const float*)d_in[5];
    const float* w2   = (const float*)d_in[6];
    const float* as2  = (const float*)d_in[7];
    const float* ad2  = (const float*)d_in[8];
    const float* b2   = (const float*)d_in[9];
    const float* mw1  = (const float*)d_in[10];
    const float* mb1  = (const float*)d_in[11];
    const float* mw2  = (const float*)d_in[12];
    const float* mb2  = (const float*)d_in[13];
    float* out = (float*)d_out;

    const int N = N_NODES, E = N_EDGES;
    int* deg     = (int*)d_ws;           // N
    int* rowptr  = deg + N;              // N
    int* cursor  = rowptr + N;           // N
    int* loc     = cursor + N;           // N
    int* partial = loc + N;              // 512
    int* csr_src = partial + 512;        // E
    float* a1s   = (float*)(csr_src + E);// 4N
    float* a1d   = a1s + 4 * N;          // 4N
    float* h2    = a1d + 4 * N;          // 32N
    float* a2s   = h2 + 32 * N;          // N
    float* a2d   = a2s + N;              // N
    float* hf    = a2d + N;              // 32N

    const int nb = (N + 255) / 256;      // 391 scan chunks

    k_zero_deg<<<nb, 256, 0, stream>>>(deg);
    k_hist<<<(E + 255) / 256, 256, 0, stream>>>(ei, deg);
    k_scan_part<<<nb, 256, 0, stream>>>(deg, loc, partial);
    k_scan_tot<<<1, 512, 0, stream>>>(partial, nb);
    k_scan_add<<<nb, 256, 0, stream>>>(loc, partial, rowptr, cursor);
    k_scatter<<<(E + 255) / 256, 256, 0, stream>>>(ei, cursor, csr_src);

    k_node1<<<(N + 3) / 4, 256, 0, stream>>>(x, w1, as1, ad1, a1s, a1d);

    k_gat1<<<(N + 3) / 4, 256, 0, stream>>>(rowptr, deg, csr_src, x, w1, a1s, a1d,
                                            b1, w2, as2, ad2, h2, a2s, a2d);

    k_gat2<<<(N + 7) / 8, 256, 0, stream>>>(rowptr, deg, csr_src, h2, a2s, a2d, b2, hf);

    k_mlp<<<(E + 255) / 256, 256, 0, stream>>>(ei, hf, mw1, mb1, mw2, mb2, out);
}